// Round 4
// baseline (464.558 us; speedup 1.0000x reference)
//
#include <hip/hip_runtime.h>
#include <hip/hip_bf16.h>
#include <stdint.h>

typedef __attribute__((ext_vector_type(8))) __bf16 bf16x8;
typedef __attribute__((ext_vector_type(4))) __bf16 bf16x4;
typedef __attribute__((ext_vector_type(4))) float  f32x4;

#define NTOK   8192
#define DMODEL 1024
#define HDIM   4096
#define NEXP   8

__device__ __forceinline__ void glds16(const void* g, void* l) {
  __builtin_amdgcn_global_load_lds(
      (const __attribute__((address_space(1))) uint32_t*)g,
      (__attribute__((address_space(3))) uint32_t*)l, 16, 0, 0);
}

#define WAITV0() asm volatile("s_waitcnt vmcnt(0)" ::: "memory")
#define BARRIER() do { __builtin_amdgcn_sched_barrier(0); \
                       __builtin_amdgcn_s_barrier();      \
                       __builtin_amdgcn_sched_barrier(0); } while (0)

// ------------------------------------------------------------------ utils
__global__ void zero_cnt_kernel(int* cnt) {
  if (threadIdx.x < NEXP) cnt[threadIdx.x] = 0;
}

// ------------------------------------------- gating + x packing (fused)
__global__ __launch_bounds__(256) void moe_gate_pack_kernel(
    const float* __restrict__ x, const float* __restrict__ gw,
    const float* __restrict__ gb, __bf16* __restrict__ xbf,
    int* __restrict__ cnt, int* __restrict__ lists)
{
  const int lane = threadIdx.x & 63;
  const int wv   = threadIdx.x >> 6;
  const int t    = (blockIdx.x << 2) + wv;
  const float* xp = x + (size_t)t * DMODEL;

  float xr[16];
  float acc[NEXP];
#pragma unroll
  for (int e = 0; e < NEXP; ++e) acc[e] = 0.f;

#pragma unroll
  for (int j = 0; j < DMODEL / 64; ++j) {
    const int d = (j << 6) + lane;
    const float xv = xp[d];
    xr[j] = xv;
    const float4 g0 = *(const float4*)(gw + (size_t)d * NEXP);
    const float4 g1 = *(const float4*)(gw + (size_t)d * NEXP + 4);
    acc[0] = fmaf(xv, g0.x, acc[0]);
    acc[1] = fmaf(xv, g0.y, acc[1]);
    acc[2] = fmaf(xv, g0.z, acc[2]);
    acc[3] = fmaf(xv, g0.w, acc[3]);
    acc[4] = fmaf(xv, g1.x, acc[4]);
    acc[5] = fmaf(xv, g1.y, acc[5]);
    acc[6] = fmaf(xv, g1.z, acc[6]);
    acc[7] = fmaf(xv, g1.w, acc[7]);
  }
#pragma unroll
  for (int e = 0; e < NEXP; ++e) {
#pragma unroll
    for (int off = 32; off > 0; off >>= 1)
      acc[e] += __shfl_xor(acc[e], off, 64);
  }
  float l[NEXP];
#pragma unroll
  for (int e = 0; e < NEXP; ++e) l[e] = acc[e] + gb[e];
  int i1 = 0; float m1 = l[0];
#pragma unroll
  for (int e = 1; e < NEXP; ++e) if (l[e] > m1) { m1 = l[e]; i1 = e; }
  int i2 = -1; float m2 = -3.402823466e38f;
#pragma unroll
  for (int e = 0; e < NEXP; ++e) if (e != i1 && l[e] > m2) { m2 = l[e]; i2 = e; }
  const int es = i1 > i2 ? i1 : i2;       // reference: last expert in loop wins
  float s = 0.f;
#pragma unroll
  for (int e = 0; e < NEXP; ++e) s += expf(l[e] - m1);
  const float w = expf(l[es] - m1) / s;

  if (lane == 0) {
    const int pos = atomicAdd(&cnt[es], 1);
    lists[(size_t)es * NTOK + pos] = t;
  }
  __bf16* xo = xbf + (size_t)t * DMODEL;
#pragma unroll
  for (int j = 0; j < DMODEL / 64; ++j)
    xo[(j << 6) + lane] = (__bf16)(xr[j] * w);
}

// ------------------------------------------------------------------ pack W
// Transpose src [E][K][N] fp32 -> dst [E][N/128][128 n][K] bf16 (k-contig
// rows; GEMM applies the LDS swizzle at glds-source time).
template<int N, int K>
__global__ __launch_bounds__(256) void pack_w_kernel(
    const float* __restrict__ src, __bf16* __restrict__ dst)
{
  const int k0 = blockIdx.x * 64, np = blockIdx.y, e = blockIdx.z;
  const int t = threadIdx.x;
  __shared__ __bf16 sh[8192];   // 64 k x 128 n, n4 XOR-swizzled by (k&3)

  const float* sp = src + (size_t)e * K * N + (size_t)k0 * N + np * 128;
#pragma unroll
  for (int i = 0; i < 8; ++i) {
    const int id = i * 256 + t;
    const int k = id >> 5, n4 = id & 31;
    const float4 v = *(const float4*)(sp + (size_t)k * N + n4 * 4);
    const int phys = n4 ^ ((k & 3) << 3);
    bf16x4 o; o[0] = (__bf16)v.x; o[1] = (__bf16)v.y;
              o[2] = (__bf16)v.z; o[3] = (__bf16)v.w;
    *(bf16x4*)&sh[k * 128 + phys * 4] = o;
  }
  __syncthreads();

  __bf16* dbase = dst + ((size_t)(e * (N / 128) + np) * 128) * K + k0;
#pragma unroll
  for (int j2 = 0; j2 < 4; ++j2) {
    const int c = j2 * 256 + t;
    const int n = c >> 3, ks8 = c & 7;
    bf16x8 v;
#pragma unroll
    for (int j = 0; j < 8; ++j) {
      const int k = ks8 * 8 + j;
      v[j] = sh[k * 128 + (((n >> 2) ^ ((k & 3) << 3)) << 2) + (n & 3)];
    }
    *(bf16x8*)(dbase + (size_t)n * K + ks8 * 8) = v;
  }
}

// ------------------------------------------------------------------ GEMM
// m97-structure: 128x128 tile, BK=64, 4 waves, SINGLE 32KB LDS buffer,
// 2 barriers per K-step, vmcnt(0) drain. Latency hiding comes from 5
// blocks/CU (32KB LDS, VGPR capped via launch_bounds) — block-level TLP,
// the m97 mechanism (874-912 TF on 4096^3).
// LDS rows: 128B (64 bf16) = 8 granules of 16B; granule phys = q ^ (row&7)
// (G4 swizzle); glds sources pre-swizzled so LDS dest stays linear.
template<int KSTEPS, int ASTRIDE, int NOUT, bool RELU, typename OutT>
__global__ __launch_bounds__(256, 5) void moe_gemm_kernel(
    const __bf16* __restrict__ Am, const __bf16* __restrict__ Bp,
    const float* __restrict__ bias, const int* __restrict__ cnt,
    const int* __restrict__ lists, OutT* __restrict__ outp)
{
  const int e  = blockIdx.z;
  const int ce = cnt[e];
  const int m0 = blockIdx.y << 7;
  if (m0 >= ce) return;
  const int np = blockIdx.x, n0 = np << 7;
  const int* list = lists + (size_t)e * NTOK;

  const int tid = threadIdx.x, lane = tid & 63, wv = tid >> 6;
  const int wm = wv >> 1, wn = wv & 1;           // wave tile position

  __shared__ alignas(16) __bf16 lds[16384];      // A 16KB | B 16KB

  // per-thread staging: 4 A granules + 4 B granules (16B each) per K-step.
  // glds group g = wv*4+i stages chunk c = g*64+lane: row r = c>>3,
  // granule p = c&7, source k-offset = (p ^ (r&7))*8.
  const __bf16* asrc[4];
  const __bf16* bsrc[4];
#pragma unroll
  for (int i = 0; i < 4; ++i) {
    const int c = (wv * 4 + i) * 64 + lane;
    const int r = c >> 3, p = c & 7;
    const int koff = (p ^ (r & 7)) * 8;
    const int rm = m0 + r;
    const int tok = list[rm < ce ? rm : ce - 1];
    asrc[i] = Am + (size_t)tok * ASTRIDE + koff;
    bsrc[i] = Bp + ((size_t)(e * (NOUT / 128) + np) * 128 + r) * ASTRIDE + koff;
  }

  auto stage = [&](int ks) {
#pragma unroll
    for (int i = 0; i < 4; ++i)
      glds16(asrc[i] + ks * 64, lds + (wv * 4 + i) * 512);
#pragma unroll
    for (int i = 0; i < 4; ++i)
      glds16(bsrc[i] + ks * 64, lds + 8192 + (wv * 4 + i) * 512);
  };

  f32x4 acc[4][4] = {};
  const int rl = lane & 15, sl = lane >> 4;

  auto compute = [&]() {
    const char* Ab = (const char*)lds;
    const char* Bb = (const char*)lds + 16384;
#pragma unroll
    for (int kk = 0; kk < 2; ++kk) {
      bf16x8 af[4], bfv[4];
#pragma unroll
      for (int f = 0; f < 4; ++f) {
        const int r = wm * 64 + f * 16 + rl;
        af[f] = *(const bf16x8*)(Ab + r * 128 + (((kk * 4 + sl) ^ (r & 7)) << 4));
      }
#pragma unroll
      for (int f = 0; f < 4; ++f) {
        const int r = wn * 64 + f * 16 + rl;
        bfv[f] = *(const bf16x8*)(Bb + r * 128 + (((kk * 4 + sl) ^ (r & 7)) << 4));
      }
#pragma unroll
      for (int i = 0; i < 4; ++i)
#pragma unroll
        for (int j = 0; j < 4; ++j)
          acc[i][j] = __builtin_amdgcn_mfma_f32_16x16x32_bf16(af[i], bfv[j], acc[i][j], 0, 0, 0);
    }
  };

  stage(0);
  for (int ks = 0; ks < KSTEPS; ++ks) {
    WAITV0();                 // own 8 staging loads landed in LDS
    BARRIER();                // whole tile staged
    compute();
    BARRIER();                // all waves done reading before overwrite
    if (ks + 1 < KSTEPS) stage(ks + 1);
  }

  // epilogue: bias (+relu), scatter rows by token id
  const int cl = lane & 15, rh = (lane >> 4) << 2;
  float bb[4];
#pragma unroll
  for (int j = 0; j < 4; ++j)
    bb[j] = bias[(size_t)e * NOUT + n0 + wn * 64 + j * 16 + cl];
#pragma unroll
  for (int i = 0; i < 4; ++i) {
#pragma unroll
    for (int r = 0; r < 4; ++r) {
      const int gm = m0 + wm * 64 + i * 16 + rh + r;
      if (gm < ce) {
        const int tok = list[gm];
        OutT* op = outp + (size_t)tok * NOUT + n0 + wn * 64;
#pragma unroll
        for (int j = 0; j < 4; ++j) {
          float v = acc[i][j][r] + bb[j];
          if constexpr (RELU) v = fmaxf(v, 0.f);
          op[j * 16 + cl] = (OutT)v;
        }
      }
    }
  }
}

// ------------------------------------------------------------------ launch
extern "C" void kernel_launch(void* const* d_in, const int* in_sizes, int n_in,
                              void* d_out, int out_size, void* d_ws, size_t ws_size,
                              hipStream_t stream)
{
  const float* x  = (const float*)d_in[0];
  const float* gw = (const float*)d_in[1];
  const float* gb = (const float*)d_in[2];
  const float* w1 = (const float*)d_in[3];
  const float* b1 = (const float*)d_in[4];
  const float* w2 = (const float*)d_in[5];
  const float* b2 = (const float*)d_in[6];
  float* out = (float*)d_out;

  char* ws = (char*)d_ws;
  int*    cnt   = (int*)ws;                              // 32 B
  int*    lists = (int*)(ws + 65536);                    // 256 KB
  __bf16* xbf   = (__bf16*)(ws + ((size_t)1   << 20));   // 16 MB
  __bf16* hmat  = (__bf16*)(ws + ((size_t)17  << 20));   // 64 MB
  __bf16* w1p   = (__bf16*)(ws + ((size_t)81  << 20));   // 64 MB
  __bf16* w2p   = (__bf16*)(ws + ((size_t)145 << 20));   // 64 MB

  zero_cnt_kernel<<<1, 64, 0, stream>>>(cnt);
  moe_gate_pack_kernel<<<NTOK / 4, 256, 0, stream>>>(x, gw, gb, xbf, cnt, lists);
  pack_w_kernel<HDIM, DMODEL><<<dim3(DMODEL / 64, HDIM / 128, NEXP), 256, 0, stream>>>(w1, w1p);
  pack_w_kernel<DMODEL, HDIM><<<dim3(HDIM / 64, DMODEL / 128, NEXP), 256, 0, stream>>>(w2, w2p);
  moe_gemm_kernel<DMODEL / 64, DMODEL, HDIM, true, __bf16>
      <<<dim3(HDIM / 128, NTOK / 128, NEXP), 256, 0, stream>>>(
          xbf, w1p, b1, cnt, lists, hmat);
  moe_gemm_kernel<HDIM / 64, HDIM, DMODEL, false, float>
      <<<dim3(DMODEL / 128, NTOK / 128, NEXP), 256, 0, stream>>>(
          hmat, w2p, b2, cnt, lists, out);
}

// Round 5
// 408.487 us; speedup vs baseline: 1.1373x; 1.1373x over previous
//
#include <hip/hip_runtime.h>
#include <hip/hip_bf16.h>
#include <stdint.h>

typedef __attribute__((ext_vector_type(8))) __bf16 bf16x8;
typedef __attribute__((ext_vector_type(4))) __bf16 bf16x4;
typedef __attribute__((ext_vector_type(4))) float  f32x4;

#define NTOK   8192
#define DMODEL 1024
#define HDIM   4096
#define NEXP   8

__device__ __forceinline__ void glds16(const void* g, void* l) {
  __builtin_amdgcn_global_load_lds(
      (const __attribute__((address_space(1))) uint32_t*)g,
      (__attribute__((address_space(3))) uint32_t*)l, 16, 0, 0);
}

#define WAITV(N) asm volatile("s_waitcnt vmcnt(" #N ")" ::: "memory")
#define SBAR()  do { __builtin_amdgcn_sched_barrier(0); \
                     __builtin_amdgcn_s_barrier();      \
                     __builtin_amdgcn_sched_barrier(0); } while (0)

// ------------------------------------------------------------------ utils
__global__ void zero_cnt_kernel(int* cnt) {
  if (threadIdx.x < NEXP) cnt[threadIdx.x] = 0;
}

// base[e+1] = base[e] + round128(cnt[e])
__global__ void prefix_kernel(const int* __restrict__ cnt, int* __restrict__ base) {
  if (threadIdx.x == 0) {
    int b = 0;
    base[0] = 0;
    for (int e = 0; e < NEXP; ++e) {
      b += (cnt[e] + 127) & ~127;
      base[e + 1] = b;
    }
  }
}

// ------------------------------------------------------------------ gating
// One wave per token: logits, softmax, top-2; chosen expert = max index of
// top-2 (reference's where() overwrite order); weight = its softmax score.
// Emits meta[t] = (es<<13)|pos and wgt[t] = w.
__global__ __launch_bounds__(256) void moe_gate_kernel(
    const float* __restrict__ x, const float* __restrict__ gw,
    const float* __restrict__ gb, float* __restrict__ wgt,
    int* __restrict__ cnt, int* __restrict__ meta)
{
  const int lane = threadIdx.x & 63;
  const int wv   = threadIdx.x >> 6;
  const int t    = (blockIdx.x << 2) + wv;
  const float* xp = x + (size_t)t * DMODEL;

  float acc[NEXP];
#pragma unroll
  for (int e = 0; e < NEXP; ++e) acc[e] = 0.f;

#pragma unroll
  for (int j = 0; j < DMODEL / 64; ++j) {
    const int d = (j << 6) + lane;
    const float xv = xp[d];
    const float4 g0 = *(const float4*)(gw + (size_t)d * NEXP);
    const float4 g1 = *(const float4*)(gw + (size_t)d * NEXP + 4);
    acc[0] = fmaf(xv, g0.x, acc[0]);
    acc[1] = fmaf(xv, g0.y, acc[1]);
    acc[2] = fmaf(xv, g0.z, acc[2]);
    acc[3] = fmaf(xv, g0.w, acc[3]);
    acc[4] = fmaf(xv, g1.x, acc[4]);
    acc[5] = fmaf(xv, g1.y, acc[5]);
    acc[6] = fmaf(xv, g1.z, acc[6]);
    acc[7] = fmaf(xv, g1.w, acc[7]);
  }
#pragma unroll
  for (int e = 0; e < NEXP; ++e) {
#pragma unroll
    for (int off = 32; off > 0; off >>= 1)
      acc[e] += __shfl_xor(acc[e], off, 64);
  }
  if (lane == 0) {
    float l[NEXP];
#pragma unroll
    for (int e = 0; e < NEXP; ++e) l[e] = acc[e] + gb[e];
    int i1 = 0; float m1 = l[0];
#pragma unroll
    for (int e = 1; e < NEXP; ++e) if (l[e] > m1) { m1 = l[e]; i1 = e; }
    int i2 = -1; float m2 = -3.402823466e38f;
#pragma unroll
    for (int e = 0; e < NEXP; ++e) if (e != i1 && l[e] > m2) { m2 = l[e]; i2 = e; }
    const int es = i1 > i2 ? i1 : i2;   // reference: last expert in loop wins
    float s = 0.f;
#pragma unroll
    for (int e = 0; e < NEXP; ++e) s += expf(l[e] - m1);
    const float w = expf(l[es] - m1) / s;
    wgt[t] = w;
    const int pos = atomicAdd(&cnt[es], 1);
    meta[t] = (es << 13) | pos;
  }
}

// -------------------------------------------------- pack x (sorted order)
// xbf[base[es]+pos] = bf16(x[t] * w); sortmap[dst] = t. 2 tokens/block.
__global__ __launch_bounds__(256) void pack_x_kernel(
    const float* __restrict__ x, const float* __restrict__ wgt,
    const int* __restrict__ meta, const int* __restrict__ base,
    __bf16* __restrict__ xbf, int* __restrict__ sortmap)
{
  const int t = blockIdx.x * 2 + (threadIdx.x >> 7);
  const int l = threadIdx.x & 127;
  const int m = meta[t];
  const int es = m >> 13, pos = m & 8191;
  const int dst = base[es] + pos;
  const float w = wgt[t];
  const float4 a = *(const float4*)(x + (size_t)t * DMODEL + l * 8);
  const float4 b = *(const float4*)(x + (size_t)t * DMODEL + l * 8 + 4);
  bf16x8 o;
  o[0] = (__bf16)(a.x * w); o[1] = (__bf16)(a.y * w);
  o[2] = (__bf16)(a.z * w); o[3] = (__bf16)(a.w * w);
  o[4] = (__bf16)(b.x * w); o[5] = (__bf16)(b.y * w);
  o[6] = (__bf16)(b.z * w); o[7] = (__bf16)(b.w * w);
  *(bf16x8*)(xbf + (size_t)dst * DMODEL + l * 8) = o;
  if (l == 0) sortmap[dst] = t;
}

// zero the pad rows of xbf (rows cnt[e]..padded(e))
__global__ __launch_bounds__(256) void zeropad_kernel(
    const int* __restrict__ cnt, const int* __restrict__ base,
    __bf16* __restrict__ xbf)
{
  const int e = blockIdx.x;
  const int c0 = cnt[e], cp = base[e + 1] - base[e];
  bf16x4 z; z[0] = z[1] = z[2] = z[3] = (__bf16)0.f;
  for (int r = c0; r < cp; ++r)
    *(bf16x4*)(xbf + (size_t)(base[e] + r) * DMODEL + threadIdx.x * 4) = z;
}

// ------------------------------------------------------------------ pack W
// Transpose src [E][K][N] fp32 -> dst [E][N/128][128 n][K] bf16.
template<int N, int K>
__global__ __launch_bounds__(256) void pack_w_kernel(
    const float* __restrict__ src, __bf16* __restrict__ dst)
{
  const int k0 = blockIdx.x * 64, np = blockIdx.y, e = blockIdx.z;
  const int t = threadIdx.x;
  __shared__ __bf16 sh[8192];   // 64 k x 128 n, n4 XOR-swizzled by (k&3)

  const float* sp = src + (size_t)e * K * N + (size_t)k0 * N + np * 128;
#pragma unroll
  for (int i = 0; i < 8; ++i) {
    const int id = i * 256 + t;
    const int k = id >> 5, n4 = id & 31;
    const float4 v = *(const float4*)(sp + (size_t)k * N + n4 * 4);
    const int phys = n4 ^ ((k & 3) << 3);
    bf16x4 o; o[0] = (__bf16)v.x; o[1] = (__bf16)v.y;
              o[2] = (__bf16)v.z; o[3] = (__bf16)v.w;
    *(bf16x4*)&sh[k * 128 + phys * 4] = o;
  }
  __syncthreads();

  __bf16* dbase = dst + ((size_t)(e * (N / 128) + np) * 128) * K + k0;
#pragma unroll
  for (int j2 = 0; j2 < 4; ++j2) {
    const int c = j2 * 256 + t;
    const int n = c >> 3, ks8 = c & 7;
    bf16x8 v;
#pragma unroll
    for (int j = 0; j < 8; ++j) {
      const int k = ks8 * 8 + j;
      v[j] = sh[k * 128 + (((n >> 2) ^ ((k & 3) << 3)) << 2) + (n & 3)];
    }
    *(bf16x8*)(dbase + (size_t)n * K + ks8 * 8) = v;
  }
}

// ------------------------------------------------------------------ GEMM
// Sorted-token GEMM: A rows are contiguous (rowbase + r). r2-schedule:
// 128x128 tile, BK=64, 4 waves, 2-stage LDS double buffer, counted vmcnt(8).
// LDS rows 128B = 8 granules of 16B, granule phys = q ^ (row&7) (swizzle at
// glds SOURCE, linear dest).
template<int KSTEPS, int ASTRIDE, int NOUT, bool RELU, bool SCATTER, typename OutT>
__global__ __launch_bounds__(256, 2) void moe_gemm_kernel(
    const __bf16* __restrict__ Am, const __bf16* __restrict__ Bp,
    const float* __restrict__ bias, const int* __restrict__ cnt,
    const int* __restrict__ base, const int* __restrict__ sortmap,
    OutT* __restrict__ outp)
{
  const int e  = blockIdx.z;
  const int ce = cnt[e];
  const int rb = base[e];
  const int cep = base[e + 1] - rb;       // padded count (multiple of 128)
  const int m0 = blockIdx.y << 7;
  if (m0 >= cep) return;
  const int np = blockIdx.x, n0 = np << 7;

  const int tid = threadIdx.x, lane = tid & 63, wv = tid >> 6;
  const int wm = wv >> 1, wn = wv & 1;

  __shared__ alignas(16) __bf16 lds[32768];   // 2 stages x (A 16KB | B 16KB)

  // per-thread staging: 4 A + 4 B granules (16B) per K-step
  const __bf16* asrc[4];
  const __bf16* bsrc[4];
#pragma unroll
  for (int i = 0; i < 4; ++i) {
    const int c = (wv * 4 + i) * 64 + lane;
    const int r = c >> 3, p = c & 7;
    const int koff = (p ^ (r & 7)) * 8;
    asrc[i] = Am + (size_t)(rb + m0 + r) * ASTRIDE + koff;
    bsrc[i] = Bp + ((size_t)(e * (NOUT / 128) + np) * 128 + r) * ASTRIDE + koff;
  }

  auto stage = [&](int buf, int ks) {
    __bf16* Ad = lds + buf * 16384;
    __bf16* Bd = Ad + 8192;
#pragma unroll
    for (int i = 0; i < 4; ++i)
      glds16(asrc[i] + ks * 64, Ad + (wv * 4 + i) * 512);
#pragma unroll
    for (int i = 0; i < 4; ++i)
      glds16(bsrc[i] + ks * 64, Bd + (wv * 4 + i) * 512);
  };

  const int cl = lane & 15, rh = (lane >> 4) << 2;
  float bb[4];
#pragma unroll
  for (int j = 0; j < 4; ++j)
    bb[j] = bias[(size_t)e * NOUT + n0 + wn * 64 + j * 16 + cl];

  f32x4 acc[4][4] = {};
  const int rl = lane & 15, sl = lane >> 4;

  auto compute = [&](int buf) {
    const char* Ab = (const char*)(lds + buf * 16384);
    const char* Bb = Ab + 16384;
#pragma unroll
    for (int kk = 0; kk < 2; ++kk) {
      bf16x8 af[4], bfv[4];
#pragma unroll
      for (int f = 0; f < 4; ++f) {
        const int r = wm * 64 + f * 16 + rl;
        af[f] = *(const bf16x8*)(Ab + r * 128 + (((kk * 4 + sl) ^ (r & 7)) << 4));
      }
#pragma unroll
      for (int f = 0; f < 4; ++f) {
        const int r = wn * 64 + f * 16 + rl;
        bfv[f] = *(const bf16x8*)(Bb + r * 128 + (((kk * 4 + sl) ^ (r & 7)) << 4));
      }
#pragma unroll
      for (int i = 0; i < 4; ++i)
#pragma unroll
        for (int j = 0; j < 4; ++j)
          acc[i][j] = __builtin_amdgcn_mfma_f32_16x16x32_bf16(af[i], bfv[j], acc[i][j], 0, 0, 0);
    }
  };

  stage(0, 0);
  int cur = 0;
  for (int ks = 0; ks < KSTEPS; ++ks) {
    if (ks + 1 < KSTEPS) {
      stage(cur ^ 1, ks + 1);          // next tile's 8 loads stay in flight
      WAITV(8);                        // current tile's loads complete
    } else {
      WAITV(0);
    }
    SBAR();                            // tile staged for all waves
    compute(cur);
    __builtin_amdgcn_sched_barrier(0);
    __builtin_amdgcn_s_barrier();      // all waves done reading before reuse
    cur ^= 1;
  }

  // epilogue
#pragma unroll
  for (int i = 0; i < 4; ++i) {
#pragma unroll
    for (int r = 0; r < 4; ++r) {
      const int gm = m0 + wm * 64 + i * 16 + rh + r;
      if constexpr (SCATTER) {
        if (gm < ce) {
          const int tok = sortmap[rb + gm];
          OutT* op = outp + (size_t)tok * NOUT + n0 + wn * 64;
#pragma unroll
          for (int j = 0; j < 4; ++j)
            op[j * 16 + cl] = (OutT)(acc[i][j][r] + bb[j]);
        }
      } else {
        // sorted contiguous write; pad rows get 0 (consumed by GEMM2)
        OutT* op = outp + (size_t)(rb + gm) * NOUT + n0 + wn * 64;
        const bool live = gm < ce;
#pragma unroll
        for (int j = 0; j < 4; ++j) {
          float v = acc[i][j][r] + bb[j];
          if constexpr (RELU) v = fmaxf(v, 0.f);
          op[j * 16 + cl] = live ? (OutT)v : (OutT)0.f;
        }
      }
    }
  }
}

// ------------------------------------------------------------------ launch
extern "C" void kernel_launch(void* const* d_in, const int* in_sizes, int n_in,
                              void* d_out, int out_size, void* d_ws, size_t ws_size,
                              hipStream_t stream)
{
  const float* x  = (const float*)d_in[0];
  const float* gw = (const float*)d_in[1];
  const float* gb = (const float*)d_in[2];
  const float* w1 = (const float*)d_in[3];
  const float* b1 = (const float*)d_in[4];
  const float* w2 = (const float*)d_in[5];
  const float* b2 = (const float*)d_in[6];
  float* out = (float*)d_out;

  char* ws = (char*)d_ws;
  int*    cnt     = (int*)ws;                               // 32 B
  int*    base    = (int*)(ws + 256);                       // 9 ints
  int*    meta    = (int*)(ws + 4096);                      // 32 KB
  float*  wgt     = (float*)(ws + 40960);                   // 32 KB
  int*    sortmap = (int*)(ws + 81920);                     // 37 KB
  __bf16* xbf     = (__bf16*)(ws + ((size_t)1  << 20));     // 18.9 MB (9216 rows)
  __bf16* hmat    = (__bf16*)(ws + ((size_t)20 << 20));     // 72 MiB  (9216 rows)
  __bf16* wp      = (__bf16*)(ws + ((size_t)92 << 20));     // 64 MiB (w1p, then w2p)

  zero_cnt_kernel<<<1, 64, 0, stream>>>(cnt);
  moe_gate_kernel<<<NTOK / 4, 256, 0, stream>>>(x, gw, gb, wgt, cnt, meta);
  prefix_kernel<<<1, 64, 0, stream>>>(cnt, base);
  pack_x_kernel<<<NTOK / 2, 256, 0, stream>>>(x, wgt, meta, base, xbf, sortmap);
  zeropad_kernel<<<NEXP, 256, 0, stream>>>(cnt, base, xbf);

  pack_w_kernel<HDIM, DMODEL><<<dim3(DMODEL / 64, HDIM / 128, NEXP), 256, 0, stream>>>(w1, wp);
  moe_gemm_kernel<DMODEL / 64, DMODEL, HDIM, true, false, __bf16>
      <<<dim3(HDIM / 128, NTOK / 128, NEXP), 256, 0, stream>>>(
          xbf, wp, b1, cnt, base, sortmap, hmat);

  pack_w_kernel<DMODEL, HDIM><<<dim3(HDIM / 64, DMODEL / 128, NEXP), 256, 0, stream>>>(w2, wp);
  moe_gemm_kernel<HDIM / 64, HDIM, DMODEL, false, true, float>
      <<<dim3(DMODEL / 128, NTOK / 128, NEXP), 256, 0, stream>>>(
          hmat, wp, b2, cnt, base, sortmap, out);
}